// Round 18
// baseline (830.855 us; speedup 1.0000x reference)
//
#include <hip/hip_runtime.h>
#include <math.h>

#define BATCH 131072
#define NTOT 320

typedef __attribute__((ext_vector_type(8))) short short8;
typedef __attribute__((ext_vector_type(4))) float f32x4;

// ---- ws layout (float offsets) ----
#define WS_D22   0          // 32*64
#define WS_VR    2048       // 320*64
#define WS_T     22528      // 320*64
#define WS_H     43008      // 320*320
#define WS_E     145408     // 128*128
#define WS_EINV  161792     // 128*128
#define WS_WEXT  178176     // 128*256  WexT[m][k]
#define WS_D11   210944     // 64*64
#define WS_ILAM  215040     // 64
#define WS_BFU   215104     // ushort region below
#define U_WATH 0            // 64*256
#define U_WATL 16384        // 64*256
#define U_WOT  32768        // 32*256
#define U_WSPH 40960        // 128*256
#define U_WSPL 73728        // 128*256
// transient small-matrix scratch inside WS_H (free until k_H runs):
#define WS_M    (WS_H)          // 32*32  M
#define WS_A32M (WS_H + 1024)   // 32*32  I+M -> Minv (in place)
#define WS_RC   (WS_H + 2048)   // 64*64  R_cal -> Rinv (in place)

__device__ inline unsigned short f2bf(float x){
    unsigned u = __builtin_bit_cast(unsigned, x);
    u += 0x7FFFu + ((u >> 16) & 1u);
    return (unsigned short)(u >> 16);
}
__device__ inline float bf2f(unsigned short h){
    unsigned u = ((unsigned)h) << 16;
    return __builtin_bit_cast(float, u);
}
__device__ inline float r_diag(int j) {
    return (j < 16 || j == 39) ? 100000.0f : 0.001f;
}

// ---------------------------------------------------------------------------
// K1a: M = X3^T X3 + Y3 - Y3^T + Z3^T Z3 + eps I ; A32 = I + M   (4 blocks)
// ---------------------------------------------------------------------------
__global__ __launch_bounds__(256) void k_der1a(
    const float* __restrict__ X3, const float* __restrict__ Y3,
    const float* __restrict__ Z3, float* __restrict__ ws)
{
    int idx = blockIdx.x*256 + threadIdx.x;
    if (idx >= 1024) return;
    int i = idx >> 5, j = idx & 31;
    float s = 0.f;
    for (int k = 0; k < 32; ++k)
        s += X3[k*32+i]*X3[k*32+j] + Z3[k*32+i]*Z3[k*32+j];
    s += Y3[i*32+j] - Y3[j*32+i];
    if (i == j) s += 0.001f;
    ws[WS_M + idx]    = s;
    ws[WS_A32M + idx] = s + (i == j ? 1.f : 0.f);
}

// ---------------------------------------------------------------------------
// K1b: GJ32, 1024 threads, one element/thread in LDS, 2 barriers/iter (proven)
// ---------------------------------------------------------------------------
__global__ __launch_bounds__(1024) void k_gj32(float* __restrict__ ws)
{
    __shared__ float A32[32*33];
    const int t = threadIdx.x;
    const int i = t >> 5, j = t & 31;
    A32[i*33+j] = ws[WS_A32M + i*32 + j];
    __syncthreads();
    for (int k = 0; k < 32; ++k) {
        float ip = 1.f / A32[k*33+k];
        float f  = A32[i*33+k];
        float pj = A32[k*33+j];
        __syncthreads();
        float nv;
        if (i == k) nv = (j == k) ? ip : pj*ip;
        else        nv = (j == k) ? (-f*ip) : (A32[i*33+j] - f*ip*pj);
        A32[i*33+j] = nv;
        __syncthreads();
    }
    ws[WS_A32M + i*32 + j] = A32[i*33+j];
}

// ---------------------------------------------------------------------------
// K1c: D22 (-> ws), R_cal (-> ws[WS_RC]).  1 block, 512 threads. (proven)
// ---------------------------------------------------------------------------
__global__ __launch_bounds__(512) void k_der1b(
    const float* __restrict__ Z3, float* __restrict__ ws)
{
    __shared__ float Ms[1024], Mi[1024], D22s[2048];
    const int t = threadIdx.x;
    for (int idx = t; idx < 1024; idx += 512) {
        Ms[idx] = ws[WS_M + idx];
        Mi[idx] = ws[WS_A32M + idx];
    }
    __syncthreads();
    for (int idx = t; idx < 2048; idx += 512) {
        int i = idx >> 6, j = idx & 63;
        float s = 0.f;
        if (j < 32) {
            for (int k = 0; k < 32; ++k) {
                float im = (k == j ? 1.f : 0.f) - Ms[k*32+j];
                s += Mi[i*32+k]*im;
            }
        } else {
            int jj = j - 32;
            for (int k = 0; k < 32; ++k) s += Mi[i*32+k]*Z3[jj*32+k];
            s *= -2.f;
        }
        float d22 = s * sqrtf(r_diag(j)) * 0.31622776601683794f;
        D22s[idx] = d22;
        ws[WS_D22 + idx] = d22;
    }
    __syncthreads();
    for (int idx = t; idx < 4096; idx += 512) {
        int i = idx >> 6, j = idx & 63;
        float s = 0.f;
        for (int k = 0; k < 32; ++k) s += D22s[k*64+i]*D22s[k*64+j];
        float v = -10.f*s;
        if (i == j) v += r_diag(i);
        ws[WS_RC + idx] = v;
    }
}

// ---------------------------------------------------------------------------
// K1d: GJ64, 256 threads, q-uniform, Ar[16] register, 1 barrier/iter (proven)
// ---------------------------------------------------------------------------
__global__ __launch_bounds__(256) void k_gj64(float* __restrict__ ws)
{
    __shared__ float piv[2][64];
    __shared__ float fcol[2][64];
    __shared__ float ipd[2];
    const int t = threadIdx.x;
    const int q = t >> 6;        // 0..3, wave-uniform
    const int i = t & 63;
    const int c0 = q*16;

    float Ar[16];
    {
        const float* Rin = ws + WS_RC + i*64 + c0;
        #pragma unroll
        for (int jj = 0; jj < 4; ++jj) {
            float4 v = *(const float4*)(Rin + jj*4);
            Ar[jj*4+0]=v.x; Ar[jj*4+1]=v.y; Ar[jj*4+2]=v.z; Ar[jj*4+3]=v.w;
        }
    }

    for (int k = 0; k < 64; ++k) {
        const int b  = k & 1;
        const int kq = k >> 4;
        const int kj = k & 15;

        float f_own = Ar[0];
        #pragma unroll
        for (int jj = 1; jj < 16; ++jj) f_own = (jj == kj) ? Ar[jj] : f_own;

        if (q == kq) fcol[b][i] = f_own;
        if (i == k) {
            #pragma unroll
            for (int jj = 0; jj < 4; ++jj) {
                float4 v;
                v.x = Ar[jj*4+0] + ((q==kq && jj*4+0==kj) ? 1.f : 0.f);
                v.y = Ar[jj*4+1] + ((q==kq && jj*4+1==kj) ? 1.f : 0.f);
                v.z = Ar[jj*4+2] + ((q==kq && jj*4+2==kj) ? 1.f : 0.f);
                v.w = Ar[jj*4+3] + ((q==kq && jj*4+3==kj) ? 1.f : 0.f);
                *(float4*)(&piv[b][c0 + jj*4]) = v;
            }
            if (q == kq) ipd[b] = 1.f / f_own;
        }
        __syncthreads();

        const float ipv = ipd[b];
        if (i == k) {
            #pragma unroll
            for (int jj = 0; jj < 16; ++jj)
                Ar[jj] = (q==kq && jj==kj) ? ipv : Ar[jj]*ipv;
        } else {
            const float g = fcol[b][i] * ipv;
            #pragma unroll
            for (int jj = 0; jj < 4; ++jj) {
                float4 pv = *(const float4*)(&piv[b][c0 + jj*4]);  // broadcast
                Ar[jj*4+0] -= g*pv.x;
                Ar[jj*4+1] -= g*pv.y;
                Ar[jj*4+2] -= g*pv.z;
                Ar[jj*4+3] -= g*pv.w;
            }
        }
    }

    {
        float* Rout = ws + WS_RC + i*64 + c0;
        #pragma unroll
        for (int jj = 0; jj < 4; ++jj) {
            float4 v;
            v.x=Ar[jj*4+0]; v.y=Ar[jj*4+1]; v.z=Ar[jj*4+2]; v.w=Ar[jj*4+3];
            *(float4*)(Rout + jj*4) = v;
        }
    }
}

// ---------------------------------------------------------------------------
// K1e: vec_r -> ws[WS_VR].  80 blocks x 256
// ---------------------------------------------------------------------------
__global__ __launch_bounds__(256) void k_vecr(
    const float* __restrict__ B2, const float* __restrict__ C2,
    const float* __restrict__ D21, const float* __restrict__ D12,
    float* __restrict__ ws)
{
    int idx = blockIdx.x*256 + threadIdx.x;
    if (idx >= 320*64) return;
    int i = idx >> 6, j = idx & 63;
    const float* D22 = ws + WS_D22;
    float v;
    if (i < 128) {
        float s = 0.f;
        for (int k = 0; k < 32; ++k) s += C2[k*128+i]*D22[k*64+j];
        v = -10.f*s;
    } else if (i < 192) {
        int ii = i - 128;
        float s = 0.f;
        for (int k = 0; k < 32; ++k) s += D21[k*64+ii]*D22[k*64+j];
        v = -10.f*s - D12[ii*64+j];
    } else {
        v = B2[(i-192)*64 + j];
    }
    ws[WS_VR+idx] = v;
}

// ---------------------------------------------------------------------------
// K1f: T = vec_r @ Rinv -> ws[WS_T].  80 blocks x 256
// ---------------------------------------------------------------------------
__global__ __launch_bounds__(256) void k_T(float* __restrict__ ws)
{
    int idx = blockIdx.x*256 + threadIdx.x;
    if (idx >= 320*64) return;
    int i = idx >> 6, j = idx & 63;
    const float* VR = ws + WS_VR + i*64;
    const float* RC = ws + WS_RC;
    float s = 0.f;
    for (int k = 0; k < 64; ++k) s += VR[k] * RC[k*64+j];
    ws[WS_T+idx] = s;
}

// ---------------------------------------------------------------------------
// K2: H = X^T X + eps I + T vec_r^T + 10 vq vq^T
// ---------------------------------------------------------------------------
__global__ void k_H(const float* __restrict__ X, const float* __restrict__ C2,
                    const float* __restrict__ D21, float* __restrict__ ws)
{
    int idx = blockIdx.x*256 + threadIdx.x;
    if (idx >= NTOT*NTOT) return;
    int i = idx / NTOT, j = idx % NTOT;
    float s = (i == j) ? 0.001f : 0.f;
    for (int k = 0; k < NTOT; ++k) s += X[k*NTOT+i]*X[k*NTOT+j];
    const float* T  = ws + WS_T;
    const float* vr = ws + WS_VR;
    float s2 = 0.f;
    for (int k = 0; k < 64; ++k) s2 += T[i*64+k]*vr[j*64+k];
    s += s2;
    if (i < 192 && j < 192) {
        float s3 = 0.f;
        for (int k = 0; k < 32; ++k) {
            float qi = (i < 128) ? C2[k*128+i] : D21[k*64 + (i-128)];
            float qj = (j < 128) ? C2[k*128+j] : D21[k*64 + (j-128)];
            s3 += qi*qj;
        }
        s += 10.f*s3;
    }
    ws[WS_H + idx] = s;
}

// ---------------------------------------------------------------------------
// K3: extract E, invLam, D11, WexT; build bf16 WaT(hi/lo), WoT
// ---------------------------------------------------------------------------
__global__ void k_extract(const float* __restrict__ Y1, const float* __restrict__ C2,
                          const float* __restrict__ D21, const float* __restrict__ D12,
                          const float* __restrict__ B2, float* __restrict__ ws)
{
    const float* H = ws + WS_H;
    unsigned short* bfb = (unsigned short*)(ws + WS_BFU);
    int tid = blockIdx.x*blockDim.x + threadIdx.x;
    int nth = gridDim.x*blockDim.x;
    for (int idx = tid; idx < 128*128; idx += nth) {
        int i = idx >> 7, j = idx & 127;
        ws[WS_E+idx] = 0.5f*(H[i*320+j] + H[(192+i)*320 + 192+j] + Y1[i*128+j] - Y1[j*128+i]);
    }
    for (int i = tid; i < 64; i += nth)
        ws[WS_ILAM+i] = 2.0f / H[(128+i)*320 + 128+i];
    for (int idx = tid; idx < 64*64; idx += nth) {
        int i = idx >> 6, j = idx & 63;
        ws[WS_D11+idx] = (j < i) ? -H[(128+i)*320 + 128+j] : 0.f;
    }
    for (int idx = tid; idx < 128*256; idx += nth) {
        int m = idx >> 8, k = idx & 255;
        ws[WS_WEXT+idx] = (k < 192) ? H[(192+m)*320 + k] : B2[m*64 + (k-192)];
    }
    for (int idx = tid; idx < 64*256; idx += nth) {
        int j = idx >> 8, k = idx & 255;
        float v;
        if (k < 128)      v = -H[(128+j)*320 + k];
        else if (k < 192) v = 0.f;
        else              v = D12[j*64 + (k-192)];
        unsigned short hi = f2bf(v);
        bfb[U_WATH+idx] = hi;
        bfb[U_WATL+idx] = f2bf(v - bf2f(hi));
    }
    const float* D22 = ws + WS_D22;
    for (int idx = tid; idx < 32*256; idx += nth) {
        int c = idx >> 8, k = idx & 255;
        float v;
        if (k < 128)      v = C2[c*128+k];
        else if (k < 192) v = D21[c*64 + (k-128)];
        else              v = D22[c*64 + (k-192)];
        bfb[U_WOT+idx] = f2bf(v);
    }
}

// ---------------------------------------------------------------------------
// K4: invert E (128x128). 1024 threads. Row slice held in FOUR NAMED float4s
// (A0..A3) — no indexable array exists, so the allocator cannot demote to
// scratch (R17: Ar[16] at 1024 thr spilled, VGPR_Count=20, 125us; arrays
// spill whenever launch_bounds caps VGPRs). All kj-dependent selects are
// per-component cndmasks. Same double-buffered publish, 1 barrier/iter.
// ---------------------------------------------------------------------------
#define PUB4(V,P,base) \
    P.x = V.x + ((hit && kj==(base+0)) ? 1.f : 0.f); \
    P.y = V.y + ((hit && kj==(base+1)) ? 1.f : 0.f); \
    P.z = V.z + ((hit && kj==(base+2)) ? 1.f : 0.f); \
    P.w = V.w + ((hit && kj==(base+3)) ? 1.f : 0.f);
#define SCL4(V,base) \
    V.x = (hit && kj==(base+0)) ? ipv : V.x*ipv; \
    V.y = (hit && kj==(base+1)) ? ipv : V.y*ipv; \
    V.z = (hit && kj==(base+2)) ? ipv : V.z*ipv; \
    V.w = (hit && kj==(base+3)) ? ipv : V.w*ipv;
#define FMS4(V,P) \
    V.x -= g*P.x; V.y -= g*P.y; V.z -= g*P.z; V.w -= g*P.w;

__global__ __launch_bounds__(1024) void k_inv128(float* __restrict__ ws)
{
    __shared__ float piv[2][128];
    __shared__ float fcol[2][128];
    __shared__ float ipd[2];
    const int t = threadIdx.x;
    const int q = t >> 7;        // 0..7, wave-uniform
    const int i = t & 127;
    const int c0 = q*16;

    float4 A0, A1, A2, A3;
    {
        const float* Ein = ws + WS_E + i*128 + c0;
        A0 = *(const float4*)(Ein);
        A1 = *(const float4*)(Ein + 4);
        A2 = *(const float4*)(Ein + 8);
        A3 = *(const float4*)(Ein + 12);
    }

    for (int k = 0; k < 128; ++k) {
        const int b  = k & 1;
        const int kq = k >> 4;
        const int kj = k & 15;
        const bool hit = (q == kq);

        // f_own = element kj of (A0..A3): 3-level mux, all static accesses
        float4 FS = (kj & 8) ? ((kj & 4) ? A3 : A2) : ((kj & 4) ? A1 : A0);
        float f01 = (kj & 1) ? FS.y : FS.x;
        float f23 = (kj & 1) ? FS.w : FS.z;
        float f_own = (kj & 2) ? f23 : f01;

        if (hit) fcol[b][i] = f_own;
        if (i == k) {
            float4 P;
            PUB4(A0, P, 0);  *(float4*)(&piv[b][c0 +  0]) = P;
            PUB4(A1, P, 4);  *(float4*)(&piv[b][c0 +  4]) = P;
            PUB4(A2, P, 8);  *(float4*)(&piv[b][c0 +  8]) = P;
            PUB4(A3, P,12);  *(float4*)(&piv[b][c0 + 12]) = P;
            if (hit) ipd[b] = 1.f / f_own;
        }
        __syncthreads();

        const float ipv = ipd[b];
        if (i == k) {
            SCL4(A0, 0); SCL4(A1, 4); SCL4(A2, 8); SCL4(A3, 12);
        } else {
            const float g = fcol[b][i] * ipv;
            float4 P0 = *(const float4*)(&piv[b][c0 +  0]);
            float4 P1 = *(const float4*)(&piv[b][c0 +  4]);
            float4 P2 = *(const float4*)(&piv[b][c0 +  8]);
            float4 P3 = *(const float4*)(&piv[b][c0 + 12]);
            FMS4(A0, P0); FMS4(A1, P1); FMS4(A2, P2); FMS4(A3, P3);
        }
    }

    {
        float* Eout = ws + WS_EINV + i*128 + c0;
        *(float4*)(Eout)      = A0;
        *(float4*)(Eout + 4)  = A1;
        *(float4*)(Eout + 8)  = A2;
        *(float4*)(Eout + 12) = A3;
    }
}

// ---------------------------------------------------------------------------
// K5: WspT[i][k] = sum_m Einv[i][m] * WexT[m][k]  -> bf16 hi/lo
// ---------------------------------------------------------------------------
__global__ __launch_bounds__(256) void k_Wsp(float* __restrict__ ws)
{
    int i = blockIdx.x;
    int k = threadIdx.x;
    const float* Einv = ws + WS_EINV + i*128;
    const float* WexT = ws + WS_WEXT;
    unsigned short* bfb = (unsigned short*)(ws + WS_BFU);
    float s = 0.f;
    for (int m = 0; m < 128; ++m) s += Einv[m] * WexT[m*256 + k];
    unsigned short hi = f2bf(s);
    bfb[U_WSPH + i*256 + k] = hi;
    bfb[U_WSPL + i*256 + k] = f2bf(s - bf2f(hi));
}

// ---------------------------------------------------------------------------
// K6: fused batch kernel (R15/R16/R17 form, passed).
// ---------------------------------------------------------------------------
__global__ __launch_bounds__(256, 4) void k_batch(
    const float* __restrict__ inpt, const float* __restrict__ state,
    const float* __restrict__ ws, float* __restrict__ out)
{
    __shared__ unsigned short zsh[64*256];    // 32768 B
    __shared__ unsigned short D11t[64*64];    // 8192 B (transposed, bf16)
    const int t = threadIdx.x;
    const int row0 = blockIdx.x * 64;
    const unsigned short* bfb = (const unsigned short*)(ws + WS_BFU);

    for (int idx = t; idx < 64*16; idx += 256) {
        int r = idx >> 4, c = idx & 15;
        const float4* p = (const float4*)(state + (size_t)(row0+r)*128 + c*8);
        float4 f0 = p[0], f1 = p[1];
        short8 h;
        h[0]=(short)f2bf(f0.x); h[1]=(short)f2bf(f0.y); h[2]=(short)f2bf(f0.z); h[3]=(short)f2bf(f0.w);
        h[4]=(short)f2bf(f1.x); h[5]=(short)f2bf(f1.y); h[6]=(short)f2bf(f1.z); h[7]=(short)f2bf(f1.w);
        *(short8*)(&zsh[r*256 + ((c ^ (r&7)) << 3)]) = h;
    }
    for (int idx = t; idx < 64*8; idx += 256) {
        int r = idx >> 3, cl = idx & 7, c = 24 + cl;
        const float4* p = (const float4*)(inpt + (size_t)(row0+r)*64 + cl*8);
        float4 f0 = p[0], f1 = p[1];
        short8 h;
        h[0]=(short)f2bf(f0.x); h[1]=(short)f2bf(f0.y); h[2]=(short)f2bf(f0.z); h[3]=(short)f2bf(f0.w);
        h[4]=(short)f2bf(f1.x); h[5]=(short)f2bf(f1.y); h[6]=(short)f2bf(f1.z); h[7]=(short)f2bf(f1.w);
        *(short8*)(&zsh[r*256 + ((c ^ (r&7)) << 3)]) = h;
    }
    for (int idx = t; idx < 4096; idx += 256) {
        int j = idx >> 6, i = idx & 63;
        float v = (i == j) ? ws[WS_ILAM + j] : ws[WS_D11 + i*64 + j];
        D11t[idx] = f2bf(v);
    }
    __syncthreads();

    const int wv = t >> 6, lane = t & 63, lr = lane & 15, lk = lane >> 4;

    {
        const unsigned short* WATH = bfb + U_WATH;
        const unsigned short* WATL = bfb + U_WATL;
        f32x4 acc1[4] = {};
        const int ks1[6] = {0,1,2,3,6,7};
        #pragma unroll
        for (int s = 0; s < 6; ++s) {
            int ks = ks1[s];
            short8 bh = *(const short8*)(&WATH[(wv*16+lr)*256 + ks*32 + lk*8]);
            short8 bl = *(const short8*)(&WATL[(wv*16+lr)*256 + ks*32 + lk*8]);
            #pragma unroll
            for (int rt = 0; rt < 4; ++rt) {
                int row = rt*16 + lr, c = ks*4 + lk;
                short8 a = *(const short8*)(&zsh[row*256 + ((c ^ (row&7)) << 3)]);
                acc1[rt] = __builtin_amdgcn_mfma_f32_16x16x32_bf16(a, bh, acc1[rt], 0, 0, 0);
                acc1[rt] = __builtin_amdgcn_mfma_f32_16x16x32_bf16(a, bl, acc1[rt], 0, 0, 0);
            }
        }
        __syncthreads();
        const int ac = wv*16 + lr;
        const int cch = 16 + (ac >> 3), coff = ac & 7;
        #pragma unroll
        for (int rt = 0; rt < 4; ++rt)
            #pragma unroll
            for (int r = 0; r < 4; ++r) {
                int row = rt*16 + lk*4 + r;
                zsh[row*256 + ((cch ^ (row&7)) << 3) + coff] = f2bf(acc1[rt][r]);
            }
    }
    __syncthreads();

    {
        const int r  = wv*16 + (lane >> 2);
        const int qq = lane & 3;
        float acc[16];
        #pragma unroll
        for (int s = 0; s < 16; ++s) {
            int i = qq*16 + s;
            int cch = 16 + (i >> 3);
            acc[s] = bf2f(zsh[r*256 + ((cch ^ (r&7)) << 3) + (i & 7)]);
        }
        float wloc[16];
        #pragma unroll
        for (int j = 0; j < 64; ++j) {
            float diag = bf2f(D11t[j*64 + j]);
            float v = acc[j & 15];
            float x = v * diag;
            float e = __expf(2.f*x);
            float wc = 1.f - __fdividef(2.f, e + 1.f);
            int src = (lane & 0x3C) | (j >> 4);
            float wj = __shfl(wc, src, 64);
            if ((j >> 4) == qq) wloc[j & 15] = wj;
            #pragma unroll
            for (int s = 0; s < 16; ++s)
                acc[s] += wj * bf2f(D11t[j*64 + qq*16 + s]);
        }
        #pragma unroll
        for (int cc = 0; cc < 2; ++cc) {
            int ch = 16 + qq*2 + cc;
            short8 h;
            #pragma unroll
            for (int e2 = 0; e2 < 8; ++e2) h[e2] = (short)f2bf(wloc[cc*8 + e2]);
            *(short8*)(&zsh[r*256 + ((ch ^ (r&7)) << 3)]) = h;
        }
    }
    __syncthreads();

    {
        const unsigned short* WOT  = bfb + U_WOT;
        const unsigned short* WSPH = bfb + U_WSPH;
        const unsigned short* WSPL = bfb + U_WSPL;
        f32x4 acc[3][4] = {};
        const int nt = (wv < 2) ? 3 : 2;
        #pragma unroll
        for (int ks = 0; ks < 8; ++ks) {
            short8 afr[4];
            #pragma unroll
            for (int rt = 0; rt < 4; ++rt) {
                int row = rt*16 + lr, c = ks*4 + lk;
                afr[rt] = *(const short8*)(&zsh[row*256 + ((c ^ (row&7)) << 3)]);
            }
            #pragma unroll
            for (int tt = 0; tt < 3; ++tt) {
                if (tt < nt) {
                    int ct = wv + tt*4;
                    if (ct < 2) {
                        short8 b = *(const short8*)(&WOT[(ct*16+lr)*256 + ks*32 + lk*8]);
                        #pragma unroll
                        for (int rt = 0; rt < 4; ++rt)
                            acc[tt][rt] = __builtin_amdgcn_mfma_f32_16x16x32_bf16(afr[rt], b, acc[tt][rt], 0, 0, 0);
                    } else {
                        short8 bh = *(const short8*)(&WSPH[((ct-2)*16+lr)*256 + ks*32 + lk*8]);
                        short8 bl = *(const short8*)(&WSPL[((ct-2)*16+lr)*256 + ks*32 + lk*8]);
                        #pragma unroll
                        for (int rt = 0; rt < 4; ++rt) {
                            acc[tt][rt] = __builtin_amdgcn_mfma_f32_16x16x32_bf16(afr[rt], bh, acc[tt][rt], 0, 0, 0);
                            acc[tt][rt] = __builtin_amdgcn_mfma_f32_16x16x32_bf16(afr[rt], bl, acc[tt][rt], 0, 0, 0);
                        }
                    }
                }
            }
        }
        float* sp = out + (size_t)BATCH*32;
        #pragma unroll
        for (int tt = 0; tt < 3; ++tt) {
            if (tt < nt) {
                int ct = wv + tt*4;
                #pragma unroll
                for (int rt = 0; rt < 4; ++rt) {
                    int rowb = row0 + rt*16 + lk*4;
                    #pragma unroll
                    for (int r = 0; r < 4; ++r) {
                        float vv = acc[tt][rt][r];
                        if (ct < 2) out[(size_t)(rowb+r)*32  + ct*16 + lr]     = vv;
                        else        sp[(size_t)(rowb+r)*128 + (ct-2)*16 + lr] = vv;
                    }
                }
            }
        }
    }
}

extern "C" void kernel_launch(void* const* d_in, const int* in_sizes, int n_in,
                              void* d_out, int out_size, void* d_ws, size_t ws_size,
                              hipStream_t stream)
{
    const float* inpt  = (const float*)d_in[0];
    const float* state = (const float*)d_in[1];
    const float* X   = (const float*)d_in[2];
    const float* Y1  = (const float*)d_in[3];
    const float* X3  = (const float*)d_in[4];
    const float* Y3  = (const float*)d_in[5];
    const float* Z3  = (const float*)d_in[6];
    const float* B2  = (const float*)d_in[7];
    const float* C2  = (const float*)d_in[8];
    const float* D21 = (const float*)d_in[9];
    const float* D12 = (const float*)d_in[10];
    float* ws  = (float*)d_ws;
    float* out = (float*)d_out;

    k_der1a<<<4, 256, 0, stream>>>(X3, Y3, Z3, ws);
    k_gj32<<<1, 1024, 0, stream>>>(ws);
    k_der1b<<<1, 512, 0, stream>>>(Z3, ws);
    k_gj64<<<1, 256, 0, stream>>>(ws);
    k_vecr<<<80, 256, 0, stream>>>(B2, C2, D21, D12, ws);
    k_T<<<80, 256, 0, stream>>>(ws);
    k_H<<<(NTOT*NTOT + 255)/256, 256, 0, stream>>>(X, C2, D21, ws);
    k_extract<<<128, 256, 0, stream>>>(Y1, C2, D21, D12, B2, ws);
    k_inv128<<<1, 1024, 0, stream>>>(ws);
    k_Wsp<<<128, 256, 0, stream>>>(ws);
    k_batch<<<BATCH/64, 256, 0, stream>>>(inpt, state, ws, out);
}

// Round 19
// 299.329 us; speedup vs baseline: 2.7757x; 2.7757x over previous
//
#include <hip/hip_runtime.h>
#include <math.h>

#define BATCH 131072
#define NTOT 320

typedef __attribute__((ext_vector_type(8))) short short8;
typedef __attribute__((ext_vector_type(4))) float f32x4;

// ---- ws layout (float offsets) ----
#define WS_D22   0          // 32*64
#define WS_VR    2048       // 320*64
#define WS_T     22528      // 320*64
#define WS_H     43008      // 320*320
#define WS_E     145408     // 128*128
#define WS_EINV  161792     // 128*128
#define WS_WEXT  178176     // 128*256  WexT[m][k]
#define WS_D11   210944     // 64*64
#define WS_ILAM  215040     // 64
#define WS_BFU   215104     // ushort region below
#define U_WATH 0            // 64*256
#define U_WATL 16384        // 64*256
#define U_WOT  32768        // 32*256
#define U_WSPH 40960        // 128*256
#define U_WSPL 73728        // 128*256
// transient scratch inside WS_H (free until k_H; reused again after k_extract):
#define WS_M    (WS_H)          // 32*32
#define WS_A32M (WS_H + 1024)   // 32*32
#define WS_RC   (WS_H + 2048)   // 64*64
// Schur scratch (WS_H free again after k_extract):
#define SC_AI   (WS_H)          // 64*64  inv(E11)
#define SC_P    (WS_H + 4096)   // 64*64  Ai@B
#define SC_S    (WS_H + 8192)   // 64*64  S -> Si (in place)
#define SC_Q    (WS_H + 12288)  // 64*64  C@Ai
#define SC_R    (WS_H + 16384)  // 64*64  Si@Q

__device__ inline unsigned short f2bf(float x){
    unsigned u = __builtin_bit_cast(unsigned, x);
    u += 0x7FFFu + ((u >> 16) & 1u);
    return (unsigned short)(u >> 16);
}
__device__ inline float bf2f(unsigned short h){
    unsigned u = ((unsigned)h) << 16;
    return __builtin_bit_cast(float, u);
}
__device__ inline float r_diag(int j) {
    return (j < 16 || j == 39) ? 100000.0f : 0.001f;
}

// ---------------------------------------------------------------------------
// K1a: M = X3^T X3 + Y3 - Y3^T + Z3^T Z3 + eps I ; A32 = I + M   (4 blocks)
// ---------------------------------------------------------------------------
__global__ __launch_bounds__(256) void k_der1a(
    const float* __restrict__ X3, const float* __restrict__ Y3,
    const float* __restrict__ Z3, float* __restrict__ ws)
{
    int idx = blockIdx.x*256 + threadIdx.x;
    if (idx >= 1024) return;
    int i = idx >> 5, j = idx & 31;
    float s = 0.f;
    for (int k = 0; k < 32; ++k)
        s += X3[k*32+i]*X3[k*32+j] + Z3[k*32+i]*Z3[k*32+j];
    s += Y3[i*32+j] - Y3[j*32+i];
    if (i == j) s += 0.001f;
    ws[WS_M + idx]    = s;
    ws[WS_A32M + idx] = s + (i == j ? 1.f : 0.f);
}

// ---------------------------------------------------------------------------
// K1b: GJ32, 1024 threads, one element/thread in LDS, 2 barriers/iter (proven)
// ---------------------------------------------------------------------------
__global__ __launch_bounds__(1024) void k_gj32(float* __restrict__ ws)
{
    __shared__ float A32[32*33];
    const int t = threadIdx.x;
    const int i = t >> 5, j = t & 31;
    A32[i*33+j] = ws[WS_A32M + i*32 + j];
    __syncthreads();
    for (int k = 0; k < 32; ++k) {
        float ip = 1.f / A32[k*33+k];
        float f  = A32[i*33+k];
        float pj = A32[k*33+j];
        __syncthreads();
        float nv;
        if (i == k) nv = (j == k) ? ip : pj*ip;
        else        nv = (j == k) ? (-f*ip) : (A32[i*33+j] - f*ip*pj);
        A32[i*33+j] = nv;
        __syncthreads();
    }
    ws[WS_A32M + i*32 + j] = A32[i*33+j];
}

// ---------------------------------------------------------------------------
// K1c: D22 (-> ws), R_cal (-> ws[WS_RC]).  1 block, 512 threads. (proven)
// ---------------------------------------------------------------------------
__global__ __launch_bounds__(512) void k_der1b(
    const float* __restrict__ Z3, float* __restrict__ ws)
{
    __shared__ float Ms[1024], Mi[1024], D22s[2048];
    const int t = threadIdx.x;
    for (int idx = t; idx < 1024; idx += 512) {
        Ms[idx] = ws[WS_M + idx];
        Mi[idx] = ws[WS_A32M + idx];
    }
    __syncthreads();
    for (int idx = t; idx < 2048; idx += 512) {
        int i = idx >> 6, j = idx & 63;
        float s = 0.f;
        if (j < 32) {
            for (int k = 0; k < 32; ++k) {
                float im = (k == j ? 1.f : 0.f) - Ms[k*32+j];
                s += Mi[i*32+k]*im;
            }
        } else {
            int jj = j - 32;
            for (int k = 0; k < 32; ++k) s += Mi[i*32+k]*Z3[jj*32+k];
            s *= -2.f;
        }
        float d22 = s * sqrtf(r_diag(j)) * 0.31622776601683794f;
        D22s[idx] = d22;
        ws[WS_D22 + idx] = d22;
    }
    __syncthreads();
    for (int idx = t; idx < 4096; idx += 512) {
        int i = idx >> 6, j = idx & 63;
        float s = 0.f;
        for (int k = 0; k < 32; ++k) s += D22s[k*64+i]*D22s[k*64+j];
        float v = -10.f*s;
        if (i == j) v += r_diag(i);
        ws[WS_RC + idx] = v;
    }
}

// ---------------------------------------------------------------------------
// K1d: GJ64 generic: 256 threads, q-uniform, Ar[16] register (PROVEN shape),
// parameterized src/dst base+stride. 1 barrier/iter.
// ---------------------------------------------------------------------------
__global__ __launch_bounds__(256) void kS_gj64g(float* __restrict__ ws,
    int srcOff, int srcStride, int dstOff, int dstStride)
{
    __shared__ float piv[2][64];
    __shared__ float fcol[2][64];
    __shared__ float ipd[2];
    const int t = threadIdx.x;
    const int q = t >> 6;        // 0..3, wave-uniform
    const int i = t & 63;
    const int c0 = q*16;

    float Ar[16];
    {
        const float* Rin = ws + srcOff + i*srcStride + c0;
        #pragma unroll
        for (int jj = 0; jj < 4; ++jj) {
            float4 v = *(const float4*)(Rin + jj*4);
            Ar[jj*4+0]=v.x; Ar[jj*4+1]=v.y; Ar[jj*4+2]=v.z; Ar[jj*4+3]=v.w;
        }
    }

    for (int k = 0; k < 64; ++k) {
        const int b  = k & 1;
        const int kq = k >> 4;
        const int kj = k & 15;

        float f_own = Ar[0];
        #pragma unroll
        for (int jj = 1; jj < 16; ++jj) f_own = (jj == kj) ? Ar[jj] : f_own;

        if (q == kq) fcol[b][i] = f_own;
        if (i == k) {
            #pragma unroll
            for (int jj = 0; jj < 4; ++jj) {
                float4 v;
                v.x = Ar[jj*4+0] + ((q==kq && jj*4+0==kj) ? 1.f : 0.f);
                v.y = Ar[jj*4+1] + ((q==kq && jj*4+1==kj) ? 1.f : 0.f);
                v.z = Ar[jj*4+2] + ((q==kq && jj*4+2==kj) ? 1.f : 0.f);
                v.w = Ar[jj*4+3] + ((q==kq && jj*4+3==kj) ? 1.f : 0.f);
                *(float4*)(&piv[b][c0 + jj*4]) = v;
            }
            if (q == kq) ipd[b] = 1.f / f_own;
        }
        __syncthreads();

        const float ipv = ipd[b];
        if (i == k) {
            #pragma unroll
            for (int jj = 0; jj < 16; ++jj)
                Ar[jj] = (q==kq && jj==kj) ? ipv : Ar[jj]*ipv;
        } else {
            const float g = fcol[b][i] * ipv;
            #pragma unroll
            for (int jj = 0; jj < 4; ++jj) {
                float4 pv = *(const float4*)(&piv[b][c0 + jj*4]);  // broadcast
                Ar[jj*4+0] -= g*pv.x;
                Ar[jj*4+1] -= g*pv.y;
                Ar[jj*4+2] -= g*pv.z;
                Ar[jj*4+3] -= g*pv.w;
            }
        }
    }

    {
        float* Rout = ws + dstOff + i*dstStride + c0;
        #pragma unroll
        for (int jj = 0; jj < 4; ++jj) {
            float4 v;
            v.x=Ar[jj*4+0]; v.y=Ar[jj*4+1]; v.z=Ar[jj*4+2]; v.w=Ar[jj*4+3];
            *(float4*)(Rout + jj*4) = v;
        }
    }
}

// ---------------------------------------------------------------------------
// K1e: vec_r -> ws[WS_VR].  80 blocks x 256
// ---------------------------------------------------------------------------
__global__ __launch_bounds__(256) void k_vecr(
    const float* __restrict__ B2, const float* __restrict__ C2,
    const float* __restrict__ D21, const float* __restrict__ D12,
    float* __restrict__ ws)
{
    int idx = blockIdx.x*256 + threadIdx.x;
    if (idx >= 320*64) return;
    int i = idx >> 6, j = idx & 63;
    const float* D22 = ws + WS_D22;
    float v;
    if (i < 128) {
        float s = 0.f;
        for (int k = 0; k < 32; ++k) s += C2[k*128+i]*D22[k*64+j];
        v = -10.f*s;
    } else if (i < 192) {
        int ii = i - 128;
        float s = 0.f;
        for (int k = 0; k < 32; ++k) s += D21[k*64+ii]*D22[k*64+j];
        v = -10.f*s - D12[ii*64+j];
    } else {
        v = B2[(i-192)*64 + j];
    }
    ws[WS_VR+idx] = v;
}

// ---------------------------------------------------------------------------
// K1f: T = vec_r @ Rinv -> ws[WS_T].  80 blocks x 256
// ---------------------------------------------------------------------------
__global__ __launch_bounds__(256) void k_T(float* __restrict__ ws)
{
    int idx = blockIdx.x*256 + threadIdx.x;
    if (idx >= 320*64) return;
    int i = idx >> 6, j = idx & 63;
    const float* VR = ws + WS_VR + i*64;
    const float* RC = ws + WS_RC;
    float s = 0.f;
    for (int k = 0; k < 64; ++k) s += VR[k] * RC[k*64+j];
    ws[WS_T+idx] = s;
}

// ---------------------------------------------------------------------------
// K2: H = X^T X + eps I + T vec_r^T + 10 vq vq^T
// ---------------------------------------------------------------------------
__global__ void k_H(const float* __restrict__ X, const float* __restrict__ C2,
                    const float* __restrict__ D21, float* __restrict__ ws)
{
    int idx = blockIdx.x*256 + threadIdx.x;
    if (idx >= NTOT*NTOT) return;
    int i = idx / NTOT, j = idx % NTOT;
    float s = (i == j) ? 0.001f : 0.f;
    for (int k = 0; k < NTOT; ++k) s += X[k*NTOT+i]*X[k*NTOT+j];
    const float* T  = ws + WS_T;
    const float* vr = ws + WS_VR;
    float s2 = 0.f;
    for (int k = 0; k < 64; ++k) s2 += T[i*64+k]*vr[j*64+k];
    s += s2;
    if (i < 192 && j < 192) {
        float s3 = 0.f;
        for (int k = 0; k < 32; ++k) {
            float qi = (i < 128) ? C2[k*128+i] : D21[k*64 + (i-128)];
            float qj = (j < 128) ? C2[k*128+j] : D21[k*64 + (j-128)];
            s3 += qi*qj;
        }
        s += 10.f*s3;
    }
    ws[WS_H + idx] = s;
}

// ---------------------------------------------------------------------------
// K3: extract E, invLam, D11, WexT; build bf16 WaT(hi/lo), WoT
// ---------------------------------------------------------------------------
__global__ void k_extract(const float* __restrict__ Y1, const float* __restrict__ C2,
                          const float* __restrict__ D21, const float* __restrict__ D12,
                          const float* __restrict__ B2, float* __restrict__ ws)
{
    const float* H = ws + WS_H;
    unsigned short* bfb = (unsigned short*)(ws + WS_BFU);
    int tid = blockIdx.x*blockDim.x + threadIdx.x;
    int nth = gridDim.x*blockDim.x;
    for (int idx = tid; idx < 128*128; idx += nth) {
        int i = idx >> 7, j = idx & 127;
        ws[WS_E+idx] = 0.5f*(H[i*320+j] + H[(192+i)*320 + 192+j] + Y1[i*128+j] - Y1[j*128+i]);
    }
    for (int i = tid; i < 64; i += nth)
        ws[WS_ILAM+i] = 2.0f / H[(128+i)*320 + 128+i];
    for (int idx = tid; idx < 64*64; idx += nth) {
        int i = idx >> 6, j = idx & 63;
        ws[WS_D11+idx] = (j < i) ? -H[(128+i)*320 + 128+j] : 0.f;
    }
    for (int idx = tid; idx < 128*256; idx += nth) {
        int m = idx >> 8, k = idx & 255;
        ws[WS_WEXT+idx] = (k < 192) ? H[(192+m)*320 + k] : B2[m*64 + (k-192)];
    }
    for (int idx = tid; idx < 64*256; idx += nth) {
        int j = idx >> 8, k = idx & 255;
        float v;
        if (k < 128)      v = -H[(128+j)*320 + k];
        else if (k < 192) v = 0.f;
        else              v = D12[j*64 + (k-192)];
        unsigned short hi = f2bf(v);
        bfb[U_WATH+idx] = hi;
        bfb[U_WATL+idx] = f2bf(v - bf2f(hi));
    }
    const float* D22 = ws + WS_D22;
    for (int idx = tid; idx < 32*256; idx += nth) {
        int c = idx >> 8, k = idx & 255;
        float v;
        if (k < 128)      v = C2[c*128+k];
        else if (k < 192) v = D21[c*64 + (k-128)];
        else              v = D22[c*64 + (k-192)];
        bfb[U_WOT+idx] = f2bf(v);
    }
}

// ---------------------------------------------------------------------------
// Schur GEMM pieces (k_T-proven access pattern: row broadcast x coalesced).
// E = [A B; C D] (in WS_E, stride 128). Ai = inv(A) (SC_AI).
// ---------------------------------------------------------------------------
__global__ __launch_bounds__(256) void kS_P(float* __restrict__ ws)
{   // P = Ai @ B
    int idx = blockIdx.x*256 + threadIdx.x;
    int i = idx >> 6, j = idx & 63;
    const float* AI = ws + SC_AI + i*64;
    const float* E  = ws + WS_E;
    float s = 0.f;
    for (int k = 0; k < 64; ++k) s += AI[k] * E[k*128 + 64 + j];
    ws[SC_P + idx] = s;
}
__global__ __launch_bounds__(256) void kS_S(float* __restrict__ ws)
{   // S = D - C @ P
    int idx = blockIdx.x*256 + threadIdx.x;
    int i = idx >> 6, j = idx & 63;
    const float* E = ws + WS_E;
    const float* C = E + (64+i)*128;
    const float* P = ws + SC_P;
    float s = E[(64+i)*128 + 64 + j];
    for (int k = 0; k < 64; ++k) s -= C[k] * P[k*64 + j];
    ws[SC_S + idx] = s;
}
__global__ __launch_bounds__(256) void kS_Q(float* __restrict__ ws)
{   // Q = C @ Ai
    int idx = blockIdx.x*256 + threadIdx.x;
    int i = idx >> 6, j = idx & 63;
    const float* E = ws + WS_E;
    const float* C = E + (64+i)*128;
    const float* AI = ws + SC_AI;
    float s = 0.f;
    for (int k = 0; k < 64; ++k) s += C[k] * AI[k*64 + j];
    ws[SC_Q + idx] = s;
}
__global__ __launch_bounds__(256) void kS_R(float* __restrict__ ws)
{   // R2 = Si @ Q ; EI bottom-left = -R2
    int idx = blockIdx.x*256 + threadIdx.x;
    int i = idx >> 6, j = idx & 63;
    const float* Si = ws + SC_S + i*64;
    const float* Q  = ws + SC_Q;
    float s = 0.f;
    for (int k = 0; k < 64; ++k) s += Si[k] * Q[k*64 + j];
    ws[SC_R + idx] = s;
    ws[WS_EINV + (64+i)*128 + j] = -s;
}
__global__ __launch_bounds__(256) void kS_TL(float* __restrict__ ws)
{   // EI tl = Ai + P@R2 ; tr = -(P@Si) ; br = Si
    int idx = blockIdx.x*256 + threadIdx.x;
    int i = idx >> 6, j = idx & 63;
    const float* P  = ws + SC_P + i*64;
    const float* R2 = ws + SC_R;
    const float* Si = ws + SC_S;
    float s1 = ws[SC_AI + idx];
    float s2 = 0.f;
    for (int k = 0; k < 64; ++k) {
        s1 += P[k] * R2[k*64 + j];
        s2 += P[k] * Si[k*64 + j];
    }
    ws[WS_EINV + i*128 + j]        = s1;
    ws[WS_EINV + i*128 + 64 + j]   = -s2;
    ws[WS_EINV + (64+i)*128 + 64 + j] = Si[i*64 + j];
}

// ---------------------------------------------------------------------------
// K5: WspT[i][k] = sum_m Einv[i][m] * WexT[m][k]  -> bf16 hi/lo
// ---------------------------------------------------------------------------
__global__ __launch_bounds__(256) void k_Wsp(float* __restrict__ ws)
{
    int i = blockIdx.x;
    int k = threadIdx.x;
    const float* Einv = ws + WS_EINV + i*128;
    const float* WexT = ws + WS_WEXT;
    unsigned short* bfb = (unsigned short*)(ws + WS_BFU);
    float s = 0.f;
    for (int m = 0; m < 128; ++m) s += Einv[m] * WexT[m*256 + k];
    unsigned short hi = f2bf(s);
    bfb[U_WSPH + i*256 + k] = hi;
    bfb[U_WSPL + i*256 + k] = f2bf(s - bf2f(hi));
}

// ---------------------------------------------------------------------------
// K6: fused batch kernel (R15-R17 form, passed).
// ---------------------------------------------------------------------------
__global__ __launch_bounds__(256, 4) void k_batch(
    const float* __restrict__ inpt, const float* __restrict__ state,
    const float* __restrict__ ws, float* __restrict__ out)
{
    __shared__ unsigned short zsh[64*256];    // 32768 B
    __shared__ unsigned short D11t[64*64];    // 8192 B (transposed, bf16)
    const int t = threadIdx.x;
    const int row0 = blockIdx.x * 64;
    const unsigned short* bfb = (const unsigned short*)(ws + WS_BFU);

    for (int idx = t; idx < 64*16; idx += 256) {
        int r = idx >> 4, c = idx & 15;
        const float4* p = (const float4*)(state + (size_t)(row0+r)*128 + c*8);
        float4 f0 = p[0], f1 = p[1];
        short8 h;
        h[0]=(short)f2bf(f0.x); h[1]=(short)f2bf(f0.y); h[2]=(short)f2bf(f0.z); h[3]=(short)f2bf(f0.w);
        h[4]=(short)f2bf(f1.x); h[5]=(short)f2bf(f1.y); h[6]=(short)f2bf(f1.z); h[7]=(short)f2bf(f1.w);
        *(short8*)(&zsh[r*256 + ((c ^ (r&7)) << 3)]) = h;
    }
    for (int idx = t; idx < 64*8; idx += 256) {
        int r = idx >> 3, cl = idx & 7, c = 24 + cl;
        const float4* p = (const float4*)(inpt + (size_t)(row0+r)*64 + cl*8);
        float4 f0 = p[0], f1 = p[1];
        short8 h;
        h[0]=(short)f2bf(f0.x); h[1]=(short)f2bf(f0.y); h[2]=(short)f2bf(f0.z); h[3]=(short)f2bf(f0.w);
        h[4]=(short)f2bf(f1.x); h[5]=(short)f2bf(f1.y); h[6]=(short)f2bf(f1.z); h[7]=(short)f2bf(f1.w);
        *(short8*)(&zsh[r*256 + ((c ^ (r&7)) << 3)]) = h;
    }
    for (int idx = t; idx < 4096; idx += 256) {
        int j = idx >> 6, i = idx & 63;
        float v = (i == j) ? ws[WS_ILAM + j] : ws[WS_D11 + i*64 + j];
        D11t[idx] = f2bf(v);
    }
    __syncthreads();

    const int wv = t >> 6, lane = t & 63, lr = lane & 15, lk = lane >> 4;

    {
        const unsigned short* WATH = bfb + U_WATH;
        const unsigned short* WATL = bfb + U_WATL;
        f32x4 acc1[4] = {};
        const int ks1[6] = {0,1,2,3,6,7};
        #pragma unroll
        for (int s = 0; s < 6; ++s) {
            int ks = ks1[s];
            short8 bh = *(const short8*)(&WATH[(wv*16+lr)*256 + ks*32 + lk*8]);
            short8 bl = *(const short8*)(&WATL[(wv*16+lr)*256 + ks*32 + lk*8]);
            #pragma unroll
            for (int rt = 0; rt < 4; ++rt) {
                int row = rt*16 + lr, c = ks*4 + lk;
                short8 a = *(const short8*)(&zsh[row*256 + ((c ^ (row&7)) << 3)]);
                acc1[rt] = __builtin_amdgcn_mfma_f32_16x16x32_bf16(a, bh, acc1[rt], 0, 0, 0);
                acc1[rt] = __builtin_amdgcn_mfma_f32_16x16x32_bf16(a, bl, acc1[rt], 0, 0, 0);
            }
        }
        __syncthreads();
        const int ac = wv*16 + lr;
        const int cch = 16 + (ac >> 3), coff = ac & 7;
        #pragma unroll
        for (int rt = 0; rt < 4; ++rt)
            #pragma unroll
            for (int r = 0; r < 4; ++r) {
                int row = rt*16 + lk*4 + r;
                zsh[row*256 + ((cch ^ (row&7)) << 3) + coff] = f2bf(acc1[rt][r]);
            }
    }
    __syncthreads();

    {
        const int r  = wv*16 + (lane >> 2);
        const int qq = lane & 3;
        float acc[16];
        #pragma unroll
        for (int s = 0; s < 16; ++s) {
            int i = qq*16 + s;
            int cch = 16 + (i >> 3);
            acc[s] = bf2f(zsh[r*256 + ((cch ^ (r&7)) << 3) + (i & 7)]);
        }
        float wloc[16];
        #pragma unroll
        for (int j = 0; j < 64; ++j) {
            float diag = bf2f(D11t[j*64 + j]);
            float v = acc[j & 15];
            float x = v * diag;
            float e = __expf(2.f*x);
            float wc = 1.f - __fdividef(2.f, e + 1.f);
            int src = (lane & 0x3C) | (j >> 4);
            float wj = __shfl(wc, src, 64);
            if ((j >> 4) == qq) wloc[j & 15] = wj;
            #pragma unroll
            for (int s = 0; s < 16; ++s)
                acc[s] += wj * bf2f(D11t[j*64 + qq*16 + s]);
        }
        #pragma unroll
        for (int cc = 0; cc < 2; ++cc) {
            int ch = 16 + qq*2 + cc;
            short8 h;
            #pragma unroll
            for (int e2 = 0; e2 < 8; ++e2) h[e2] = (short)f2bf(wloc[cc*8 + e2]);
            *(short8*)(&zsh[r*256 + ((ch ^ (r&7)) << 3)]) = h;
        }
    }
    __syncthreads();

    {
        const unsigned short* WOT  = bfb + U_WOT;
        const unsigned short* WSPH = bfb + U_WSPH;
        const unsigned short* WSPL = bfb + U_WSPL;
        f32x4 acc[3][4] = {};
        const int nt = (wv < 2) ? 3 : 2;
        #pragma unroll
        for (int ks = 0; ks < 8; ++ks) {
            short8 afr[4];
            #pragma unroll
            for (int rt = 0; rt < 4; ++rt) {
                int row = rt*16 + lr, c = ks*4 + lk;
                afr[rt] = *(const short8*)(&zsh[row*256 + ((c ^ (row&7)) << 3)]);
            }
            #pragma unroll
            for (int tt = 0; tt < 3; ++tt) {
                if (tt < nt) {
                    int ct = wv + tt*4;
                    if (ct < 2) {
                        short8 b = *(const short8*)(&WOT[(ct*16+lr)*256 + ks*32 + lk*8]);
                        #pragma unroll
                        for (int rt = 0; rt < 4; ++rt)
                            acc[tt][rt] = __builtin_amdgcn_mfma_f32_16x16x32_bf16(afr[rt], b, acc[tt][rt], 0, 0, 0);
                    } else {
                        short8 bh = *(const short8*)(&WSPH[((ct-2)*16+lr)*256 + ks*32 + lk*8]);
                        short8 bl = *(const short8*)(&WSPL[((ct-2)*16+lr)*256 + ks*32 + lk*8]);
                        #pragma unroll
                        for (int rt = 0; rt < 4; ++rt) {
                            acc[tt][rt] = __builtin_amdgcn_mfma_f32_16x16x32_bf16(afr[rt], bh, acc[tt][rt], 0, 0, 0);
                            acc[tt][rt] = __builtin_amdgcn_mfma_f32_16x16x32_bf16(afr[rt], bl, acc[tt][rt], 0, 0, 0);
                        }
                    }
                }
            }
        }
        float* sp = out + (size_t)BATCH*32;
        #pragma unroll
        for (int tt = 0; tt < 3; ++tt) {
            if (tt < nt) {
                int ct = wv + tt*4;
                #pragma unroll
                for (int rt = 0; rt < 4; ++rt) {
                    int rowb = row0 + rt*16 + lk*4;
                    #pragma unroll
                    for (int r = 0; r < 4; ++r) {
                        float vv = acc[tt][rt][r];
                        if (ct < 2) out[(size_t)(rowb+r)*32  + ct*16 + lr]     = vv;
                        else        sp[(size_t)(rowb+r)*128 + (ct-2)*16 + lr] = vv;
                    }
                }
            }
        }
    }
}

extern "C" void kernel_launch(void* const* d_in, const int* in_sizes, int n_in,
                              void* d_out, int out_size, void* d_ws, size_t ws_size,
                              hipStream_t stream)
{
    const float* inpt  = (const float*)d_in[0];
    const float* state = (const float*)d_in[1];
    const float* X   = (const float*)d_in[2];
    const float* Y1  = (const float*)d_in[3];
    const float* X3  = (const float*)d_in[4];
    const float* Y3  = (const float*)d_in[5];
    const float* Z3  = (const float*)d_in[6];
    const float* B2  = (const float*)d_in[7];
    const float* C2  = (const float*)d_in[8];
    const float* D21 = (const float*)d_in[9];
    const float* D12 = (const float*)d_in[10];
    float* ws  = (float*)d_ws;
    float* out = (float*)d_out;

    k_der1a<<<4, 256, 0, stream>>>(X3, Y3, Z3, ws);
    k_gj32<<<1, 1024, 0, stream>>>(ws);
    k_der1b<<<1, 512, 0, stream>>>(Z3, ws);
    kS_gj64g<<<1, 256, 0, stream>>>(ws, WS_RC, 64, WS_RC, 64);   // Rinv
    k_vecr<<<80, 256, 0, stream>>>(B2, C2, D21, D12, ws);
    k_T<<<80, 256, 0, stream>>>(ws);
    k_H<<<(NTOT*NTOT + 255)/256, 256, 0, stream>>>(X, C2, D21, ws);
    k_extract<<<128, 256, 0, stream>>>(Y1, C2, D21, D12, B2, ws);
    // Schur-complement inverse of E:
    kS_gj64g<<<1, 256, 0, stream>>>(ws, WS_E, 128, SC_AI, 64);   // Ai = inv(E11)
    kS_P<<<16, 256, 0, stream>>>(ws);                            // P = Ai@B
    kS_S<<<16, 256, 0, stream>>>(ws);                            // S = D - C@P
    kS_gj64g<<<1, 256, 0, stream>>>(ws, SC_S, 64, SC_S, 64);     // Si = inv(S)
    kS_Q<<<16, 256, 0, stream>>>(ws);                            // Q = C@Ai
    kS_R<<<16, 256, 0, stream>>>(ws);                            // R2 = Si@Q; bl
    kS_TL<<<16, 256, 0, stream>>>(ws);                           // tl, tr, br
    k_Wsp<<<128, 256, 0, stream>>>(ws);
    k_batch<<<BATCH/64, 256, 0, stream>>>(inpt, state, ws, out);
}